// Round 9
// baseline (67.447 us; speedup 1.0000x reference)
//
#include <hip/hip_runtime.h>

constexpr int N = 512;   // number of samples
constexpr int D = 256;   // feature dim
constexpr int NB = 256;  // blocks (2 anchors each)
#define MARGIN 1.0f

// d_ws layout: part[512] floats (sum,cnt per block) | flags[256] ints.
// flags start POISONED (0xAAAAAAAA) -> block b posts 0xC0FFEE00|b (never
// equals poison), block 0 acquire-polls all flags, reduces, writes out.
// Single dispatch: no finalize kernel, no memset needed.

#define ACC(S, A, B)                                                   \
  { float ex = A.x - B.x, ey = A.y - B.y, ez = A.z - B.z,              \
          ew = A.w - B.w;                                              \
    S += ex * ex + ey * ey + ez * ez + ew * ew; }

__global__ __launch_bounds__(1024, 4) void triplet_fused(
    const float* __restrict__ x, const int* __restrict__ tgt,
    float* __restrict__ part, int* __restrict__ flags,
    float* __restrict__ out) {
  __shared__ __align__(16) float m0[N], m1[N];  // dist rows, +INF at positives
  __shared__ float cl0[N], cl1[N];              // compacted c = d_ap + margin
  __shared__ int stgt[N];                       // targets staged in LDS
  __shared__ int nv0, nv1;
  __shared__ float wred[32];                    // 16 waves x {sum | cnt}

  const int b = blockIdx.x;
  const int i0 = 2 * b, i1 = 2 * b + 1;
  const int tid = threadIdx.x;                  // 1024 threads = 16 waves
  const int wave = tid >> 6, lane = tid & 63;
  const int sub = lane & 15, rg = lane >> 4;    // chunk-in-row, row-in-group

  if (tid == 0) { nv0 = 0; nv1 = 0; }
  if (tid < N / 2) ((int2*)stgt)[tid] = ((const int2*)tgt)[tid];

  // both anchors' row fragments, loop-invariant registers (L1-resident)
  const float4* xa = (const float4*)(x + (size_t)i0 * D);
  const float4* xc = (const float4*)(x + (size_t)i1 * D);
  float4 a0 = xa[sub], a1 = xa[16 + sub], a2 = xa[32 + sub], a3 = xa[48 + sub];
  float4 c0 = xc[sub], c1 = xc[16 + sub], c2 = xc[32 + sub], c3 = xc[48 + sub];
  __syncthreads();                              // nv + stgt visible
  const int t0 = stgt[i0], t1 = stgt[i1];

  // Wave w covers rows [w*32, w*32+32): 4 rows/iter (one per 16-lane group).
  // Per-block rotation decorrelates the blocks' L2 streams.
  const int rot = (b * 171) & (N - 1);
  const int rbase = wave * 32 + rg;
  #pragma unroll 2
  for (int it = 0; it < 8; ++it) {
    const int r = (rbase + it * 4 + rot) & (N - 1);
    const float4* xr = (const float4*)(x + (size_t)r * D);
    float4 b0 = xr[sub];
    float4 b1 = xr[16 + sub];
    float4 b2 = xr[32 + sub];
    float4 b3 = xr[48 + sub];
    float sa = 0.f, sb = 0.f;                   // d^2 partials, both anchors
    ACC(sa, a0, b0); ACC(sa, a1, b1); ACC(sa, a2, b2); ACC(sa, a3, b3);
    ACC(sb, c0, b0); ACC(sb, c1, b1); ACC(sb, c2, b2); ACC(sb, c3, b3);
    // reduce over the 16-lane group (lane sub==0 gets clean value)
    #pragma unroll
    for (int off = 8; off > 0; off >>= 1) {
      sa += __shfl_down(sa, off);
      sb += __shfl_down(sb, off);
    }
    if (sub == 0) {
      const int tj = stgt[r];
      float da = sqrtf(fmaxf(sa, 1e-16f));
      float db = sqrtf(fmaxf(sb, 1e-16f));
      m0[r] = (tj != t0) ? da : __builtin_inff();
      m1[r] = (tj != t1) ? db : __builtin_inff();
      if (tj == t0 && r != i0) { int s = atomicAdd(&nv0, 1); cl0[s] = da + MARGIN; }
      if (tj == t1 && r != i1) { int s = atomicAdd(&nv1, 1); cl1[s] = db + MARGIN; }
    }
  }
  __syncthreads();

  // triplet phase: thread pair (tid, tid+512) shares element e=tid&511 and
  // splits each clist between them (v = half, half+2, ...)
  float sum = 0.f, cnt = 0.f;
  const int e = tid & 511, half = tid >> 9;
  const float mk0 = m0[e], mk1 = m1[e];
  const int n0 = nv0, n1 = nv1;
  for (int v = half; v < n0; v += 2) {
    float a = cl0[v] - mk0;                     // cl0[v] is LDS broadcast
    sum += fmaxf(a, 0.f);
    cnt += (a > 1e-16f ? 1.f : 0.f);
  }
  for (int v = half; v < n1; v += 2) {
    float a = cl1[v] - mk1;
    sum += fmaxf(a, 0.f);
    cnt += (a > 1e-16f ? 1.f : 0.f);
  }

  // block reduction over 16 waves, then publish partial + flag
  #pragma unroll
  for (int off = 32; off > 0; off >>= 1) {
    sum += __shfl_down(sum, off);
    cnt += __shfl_down(cnt, off);
  }
  if (lane == 0) { wred[wave] = sum; wred[16 + wave] = cnt; }
  __syncthreads();
  if (tid == 0) {
    float s = 0.f, c = 0.f;
    #pragma unroll
    for (int w = 0; w < 16; ++w) { s += wred[w]; c += wred[16 + w]; }
    __hip_atomic_store(&part[2 * b], s, __ATOMIC_RELAXED, __HIP_MEMORY_SCOPE_AGENT);
    __hip_atomic_store(&part[2 * b + 1], c, __ATOMIC_RELAXED, __HIP_MEMORY_SCOPE_AGENT);
    __hip_atomic_store(&flags[b], (int)(0xC0FFEE00 | b), __ATOMIC_RELEASE,
                       __HIP_MEMORY_SCOPE_AGENT);
  }

  // block 0: wait for all partials, reduce, write result (no 2nd dispatch)
  if (b == 0) {
    if (tid < NB) {
      const int expect = (int)(0xC0FFEE00 | tid);
      while (__hip_atomic_load(&flags[tid], __ATOMIC_ACQUIRE,
                               __HIP_MEMORY_SCOPE_AGENT) != expect) {
        __builtin_amdgcn_s_sleep(4);
      }
    }
    __syncthreads();
    float s = 0.f, c = 0.f;
    if (tid < NB) {
      s = __hip_atomic_load(&part[2 * tid], __ATOMIC_RELAXED,
                            __HIP_MEMORY_SCOPE_AGENT);
      c = __hip_atomic_load(&part[2 * tid + 1], __ATOMIC_RELAXED,
                            __HIP_MEMORY_SCOPE_AGENT);
    }
    #pragma unroll
    for (int off = 32; off > 0; off >>= 1) {
      s += __shfl_down(s, off);
      c += __shfl_down(c, off);
    }
    if (lane == 0 && tid < NB) { wred[wave] = s; wred[16 + wave] = c; }
    __syncthreads();
    if (tid == 0) {
      float ts = wred[0] + wred[1] + wred[2] + wred[3];
      float tc = wred[16] + wred[17] + wred[18] + wred[19];
      out[0] = ts / (tc + 1e-16f);
    }
  }
}

extern "C" void kernel_launch(void* const* d_in, const int* in_sizes, int n_in,
                              void* d_out, int out_size, void* d_ws, size_t ws_size,
                              hipStream_t stream) {
  const float* x = (const float*)d_in[0];   // [512, 256] fp32
  const int* tgt = (const int*)d_in[1];     // [512] int32
  float* out = (float*)d_out;               // scalar fp32
  float* part = (float*)d_ws;               // 256 x {sum, cnt} partials
  int* flags = (int*)((float*)d_ws + 2 * NB);

  triplet_fused<<<NB, 1024, 0, stream>>>(x, tgt, part, flags, out);
}